// Round 1
// baseline (2616.496 us; speedup 1.0000x reference)
//
#include <hip/hip_runtime.h>

#define IN_C 256
#define HID_C 256
#define OUT_C 128
#define NUM_GRAPHS 64

// ---------------- degree / CSR build ----------------

__global__ __launch_bounds__(256) void count_deg_kernel(const int* __restrict__ dst, int E,
                                                        int* __restrict__ cnt) {
    int e = blockIdx.x * 256 + threadIdx.x;
    if (e < E) atomicAdd(&cnt[dst[e]], 1);
}

__global__ __launch_bounds__(256) void dinv_kernel(const int* __restrict__ cnt,
                                                   float* __restrict__ dinv, int N) {
    int i = blockIdx.x * 256 + threadIdx.x;
    if (i < N) dinv[i] = rsqrtf((float)(cnt[i] + 1));  // +1 self loop; deg>=1 always
}

__global__ __launch_bounds__(1024) void scan_kernel(const int* __restrict__ cnt,
                                                    int* __restrict__ rowptr, int N) {
    __shared__ int sums[1024];
    int tid = threadIdx.x;
    int chunk = (N + 1023) >> 10;
    int start = tid * chunk;
    int end = min(start + chunk, N);
    int s = 0;
    for (int i = start; i < end; ++i) s += cnt[i];
    sums[tid] = s;
    __syncthreads();
    // Hillis-Steele inclusive scan over 1024 partials
    for (int off = 1; off < 1024; off <<= 1) {
        int t = (tid >= off) ? sums[tid - off] : 0;
        __syncthreads();
        sums[tid] += t;
        __syncthreads();
    }
    int run = (tid == 0) ? 0 : sums[tid - 1];
    for (int i = start; i < end; ++i) { rowptr[i] = run; run += cnt[i]; }
    if (tid == 1023) rowptr[N] = sums[1023];
}

__global__ __launch_bounds__(256) void scatter_kernel(const int* __restrict__ src,
                                                      const int* __restrict__ dst, int E,
                                                      const int* __restrict__ rowptr,
                                                      int* __restrict__ fill,
                                                      int* __restrict__ csr) {
    int e = blockIdx.x * 256 + threadIdx.x;
    if (e < E) {
        int d = dst[e];
        int pos = rowptr[d] + atomicAdd(&fill[d], 1);
        csr[pos] = src[e];
    }
}

// ---------------- GEMM (f32) with fused dinv row-scale ----------------
// HS[r][c] = dinv[r] * sum_k X[r][k] * W[k][c];  K = 256 fixed, C in {256,128}
// BM=64, BN=64, BK=16, 256 threads, 4x4 micro-tile per thread.

__global__ __launch_bounds__(256) void gemm_scale_kernel(const float* __restrict__ X,
                                                         const float* __restrict__ W,
                                                         const float* __restrict__ dinv,
                                                         float* __restrict__ HS,
                                                         int nRows, int C) {
    __shared__ float As[16][68];  // stride 68 floats = 272B -> 16B aligned rows, pad kills conflicts
    __shared__ float Bs[16][64];

    int tid = threadIdx.x;
    int row0 = blockIdx.x << 6;
    int col0 = blockIdx.y << 6;

    int am = tid & 63, akq = tid >> 6;          // A tile loader: row am, k-quad akq
    int bk = tid >> 4, bc4 = (tid & 15) << 2;   // B tile loader: k row bk, col quad bc4
    int ty = tid >> 4, tx = tid & 15;           // compute: rows ty*4.., cols tx*4..

    int arow = row0 + am;
    bool aok = arow < nRows;
    const float* xrow = X + (size_t)(aok ? arow : (nRows - 1)) * IN_C;

    float acc[4][4] = {};

    for (int k0 = 0; k0 < IN_C; k0 += 16) {
        float4 av = aok ? *(const float4*)(xrow + k0 + (akq << 2))
                        : make_float4(0.f, 0.f, 0.f, 0.f);
        float4 bv = *(const float4*)(W + (size_t)(k0 + bk) * C + col0 + bc4);
        __syncthreads();
        As[(akq << 2) + 0][am] = av.x;
        As[(akq << 2) + 1][am] = av.y;
        As[(akq << 2) + 2][am] = av.z;
        As[(akq << 2) + 3][am] = av.w;
        *(float4*)(&Bs[bk][bc4]) = bv;
        __syncthreads();
#pragma unroll
        for (int k = 0; k < 16; ++k) {
            float4 a = *(const float4*)(&As[k][ty << 2]);
            float4 b = *(const float4*)(&Bs[k][tx << 2]);
            acc[0][0] += a.x * b.x; acc[0][1] += a.x * b.y; acc[0][2] += a.x * b.z; acc[0][3] += a.x * b.w;
            acc[1][0] += a.y * b.x; acc[1][1] += a.y * b.y; acc[1][2] += a.y * b.z; acc[1][3] += a.y * b.w;
            acc[2][0] += a.z * b.x; acc[2][1] += a.z * b.y; acc[2][2] += a.z * b.z; acc[2][3] += a.z * b.w;
            acc[3][0] += a.w * b.x; acc[3][1] += a.w * b.y; acc[3][2] += a.w * b.z; acc[3][3] += a.w * b.w;
        }
    }

#pragma unroll
    for (int i = 0; i < 4; ++i) {
        int row = row0 + (ty << 2) + i;
        if (row < nRows) {
            float s = dinv[row];
            float4 o = make_float4(acc[i][0] * s, acc[i][1] * s, acc[i][2] * s, acc[i][3] * s);
            *(float4*)(HS + (size_t)row * C + col0 + (tx << 2)) = o;
        }
    }
}

// ---------------- aggregation: OUT[v] = relu?(dinv[v]*(HS[v] + sum_{u->v} HS[u]) + b) ----------
// one wave (64 lanes) per node; lane owns C/64 contiguous channels.

template <int C, bool RELU>
__global__ __launch_bounds__(256) void aggregate_kernel(const float* __restrict__ HS,
                                                        const int* __restrict__ rowptr,
                                                        const int* __restrict__ csr,
                                                        const float* __restrict__ dinv,
                                                        const float* __restrict__ bias,
                                                        float* __restrict__ OUT, int N) {
    int gid = blockIdx.x * 256 + threadIdx.x;
    int v = gid >> 6;
    int lane = threadIdx.x & 63;
    if (v >= N) return;

    int beg = rowptr[v];
    int end = rowptr[v + 1];

    if constexpr (C == 256) {
        const size_t co = (size_t)(lane << 2);
        float4 acc = *(const float4*)(HS + (size_t)v * C + co);
        float4 acc2 = make_float4(0.f, 0.f, 0.f, 0.f);
        int j = beg;
        for (; j + 2 <= end; j += 2) {
            int u0 = csr[j], u1 = csr[j + 1];
            float4 a = *(const float4*)(HS + (size_t)u0 * C + co);
            float4 b = *(const float4*)(HS + (size_t)u1 * C + co);
            acc.x += a.x; acc.y += a.y; acc.z += a.z; acc.w += a.w;
            acc2.x += b.x; acc2.y += b.y; acc2.z += b.z; acc2.w += b.w;
        }
        if (j < end) {
            int u = csr[j];
            float4 a = *(const float4*)(HS + (size_t)u * C + co);
            acc.x += a.x; acc.y += a.y; acc.z += a.z; acc.w += a.w;
        }
        acc.x += acc2.x; acc.y += acc2.y; acc.z += acc2.z; acc.w += acc2.w;
        float s = dinv[v];
        float4 bb = *(const float4*)(bias + co);
        float4 o = make_float4(acc.x * s + bb.x, acc.y * s + bb.y,
                               acc.z * s + bb.z, acc.w * s + bb.w);
        if (RELU) {
            o.x = fmaxf(o.x, 0.f); o.y = fmaxf(o.y, 0.f);
            o.z = fmaxf(o.z, 0.f); o.w = fmaxf(o.w, 0.f);
        }
        *(float4*)(OUT + (size_t)v * C + co) = o;
    } else {  // C == 128
        const size_t co = (size_t)(lane << 1);
        float2 acc = *(const float2*)(HS + (size_t)v * C + co);
        float2 acc2 = make_float2(0.f, 0.f);
        int j = beg;
        for (; j + 2 <= end; j += 2) {
            int u0 = csr[j], u1 = csr[j + 1];
            float2 a = *(const float2*)(HS + (size_t)u0 * C + co);
            float2 b = *(const float2*)(HS + (size_t)u1 * C + co);
            acc.x += a.x; acc.y += a.y;
            acc2.x += b.x; acc2.y += b.y;
        }
        if (j < end) {
            int u = csr[j];
            float2 a = *(const float2*)(HS + (size_t)u * C + co);
            acc.x += a.x; acc.y += a.y;
        }
        acc.x += acc2.x; acc.y += acc2.y;
        float s = dinv[v];
        float2 bb = *(const float2*)(bias + co);
        float2 o = make_float2(acc.x * s + bb.x, acc.y * s + bb.y);
        if (RELU) { o.x = fmaxf(o.x, 0.f); o.y = fmaxf(o.y, 0.f); }
        *(float2*)(OUT + (size_t)v * C + co) = o;
    }
}

// ---------------- pooling ----------------

__global__ __launch_bounds__(256) void count_batch_kernel(const int* __restrict__ batch, int N,
                                                          int* __restrict__ gcnt) {
    int i = blockIdx.x * 256 + threadIdx.x;
    if (i < N) atomicAdd(&gcnt[batch[i]], 1);
}

// block = 128 threads (one per channel), each block scans a contiguous chunk of nodes.
// batch is sorted, so each block flushes ~1-2 partial sums per channel.
__global__ __launch_bounds__(128) void pool_kernel(const float* __restrict__ H,
                                                   const int* __restrict__ batch,
                                                   float* __restrict__ gsum, int N) {
    const int NODES_PER_BLOCK = 256;
    int c = threadIdx.x;
    int start = blockIdx.x * NODES_PER_BLOCK;
    if (start >= N) return;
    int end = min(start + NODES_PER_BLOCK, N);
    float acc = 0.f;
    int cur = batch[start];
    for (int i = start; i < end; ++i) {
        int b = batch[i];
        if (b != cur) {
            atomicAdd(&gsum[cur * OUT_C + c], acc);
            acc = 0.f;
            cur = b;
        }
        acc += H[(size_t)i * OUT_C + c];
    }
    atomicAdd(&gsum[cur * OUT_C + c], acc);
}

__global__ __launch_bounds__(256) void finalize_kernel(const float* __restrict__ gsum,
                                                       const int* __restrict__ gcnt,
                                                       float* __restrict__ out) {
    int idx = blockIdx.x * 256 + threadIdx.x;
    if (idx < NUM_GRAPHS * OUT_C) {
        int g = idx >> 7;  // /OUT_C
        out[idx] = gsum[idx] / fmaxf((float)gcnt[g], 1.f);
    }
}

// ---------------- launch ----------------

extern "C" void kernel_launch(void* const* d_in, const int* in_sizes, int n_in,
                              void* d_out, int out_size, void* d_ws, size_t ws_size,
                              hipStream_t stream) {
    const float* x  = (const float*)d_in[0];
    const int* edge = (const int*)d_in[1];
    const int* batch = (const int*)d_in[2];
    const float* W1 = (const float*)d_in[3];
    const float* b1 = (const float*)d_in[4];
    const float* W2 = (const float*)d_in[5];
    const float* b2 = (const float*)d_in[6];
    const float* W3 = (const float*)d_in[7];
    const float* b3 = (const float*)d_in[8];

    const int N = in_sizes[0] / IN_C;
    const int E = in_sizes[1] / 2;
    const int* src = edge;
    const int* dst = edge + E;

    char* ws = (char*)d_ws;
    size_t off = 0;
    auto alloc = [&](size_t bytes) -> void* {
        void* p = ws + off;
        off += (bytes + 255) & ~(size_t)255;
        return p;
    };
    float* bufA   = (float*)alloc((size_t)N * HID_C * sizeof(float));
    float* bufB   = (float*)alloc((size_t)N * HID_C * sizeof(float));
    float* dinv   = (float*)alloc((size_t)N * sizeof(float));
    int*   cnt    = (int*)alloc((size_t)N * sizeof(int));
    int*   rowptr = (int*)alloc((size_t)(N + 1) * sizeof(int));
    int*   fill   = (int*)alloc((size_t)N * sizeof(int));
    int*   csr    = (int*)alloc((size_t)E * sizeof(int));
    float* gsum   = (float*)alloc((size_t)NUM_GRAPHS * OUT_C * sizeof(float));
    int*   gcnt   = (int*)alloc((size_t)NUM_GRAPHS * sizeof(int));

    hipMemsetAsync(cnt, 0, (size_t)N * sizeof(int), stream);
    hipMemsetAsync(fill, 0, (size_t)N * sizeof(int), stream);
    hipMemsetAsync(gsum, 0, (size_t)NUM_GRAPHS * OUT_C * sizeof(float), stream);
    hipMemsetAsync(gcnt, 0, (size_t)NUM_GRAPHS * sizeof(int), stream);

    int eb = (E + 255) / 256;
    int nb = (N + 255) / 256;
    int mt = (N + 63) / 64;
    int ab = (N * 64 + 255) / 256;  // aggregate: one wave per node

    count_deg_kernel<<<eb, 256, 0, stream>>>(dst, E, cnt);
    dinv_kernel<<<nb, 256, 0, stream>>>(cnt, dinv, N);
    scan_kernel<<<1, 1024, 0, stream>>>(cnt, rowptr, N);
    scatter_kernel<<<eb, 256, 0, stream>>>(src, dst, E, rowptr, fill, csr);

    // layer 1: x @ W1 -> bufA (scaled), aggregate -> bufB (+b1, relu)
    gemm_scale_kernel<<<dim3(mt, HID_C / 64), 256, 0, stream>>>(x, W1, dinv, bufA, N, HID_C);
    aggregate_kernel<256, true><<<ab, 256, 0, stream>>>(bufA, rowptr, csr, dinv, b1, bufB, N);

    // layer 2
    gemm_scale_kernel<<<dim3(mt, HID_C / 64), 256, 0, stream>>>(bufB, W2, dinv, bufA, N, HID_C);
    aggregate_kernel<256, true><<<ab, 256, 0, stream>>>(bufA, rowptr, csr, dinv, b2, bufB, N);

    // layer 3 (C=128, no relu)
    gemm_scale_kernel<<<dim3(mt, OUT_C / 64), 256, 0, stream>>>(bufB, W3, dinv, bufA, N, OUT_C);
    aggregate_kernel<128, false><<<ab, 256, 0, stream>>>(bufA, rowptr, csr, dinv, b3, bufB, N);

    // mean pool
    count_batch_kernel<<<nb, 256, 0, stream>>>(batch, N, gcnt);
    pool_kernel<<<(N + 255) / 256, 128, 0, stream>>>(bufB, batch, gsum, N);
    finalize_kernel<<<(NUM_GRAPHS * OUT_C + 255) / 256, 256, 0, stream>>>(gsum, gcnt, (float*)d_out);
}

// Round 2
// 2113.152 us; speedup vs baseline: 1.2382x; 1.2382x over previous
//
#include <hip/hip_runtime.h>

#define IN_C 256
#define HID_C 256
#define OUT_C 128
#define NUM_GRAPHS 64

// ---------------- degree / CSR build ----------------

__global__ __launch_bounds__(256) void count_deg_kernel(const int* __restrict__ dst, int E,
                                                        int* __restrict__ cnt) {
    int e = blockIdx.x * 256 + threadIdx.x;
    if (e < E) atomicAdd(&cnt[dst[e]], 1);
}

__global__ __launch_bounds__(256) void dinv_kernel(const int* __restrict__ cnt,
                                                   float* __restrict__ dinv, int N) {
    int i = blockIdx.x * 256 + threadIdx.x;
    if (i < N) dinv[i] = rsqrtf((float)(cnt[i] + 1));  // +1 self loop; deg>=1 always
}

__global__ __launch_bounds__(1024) void scan_kernel(const int* __restrict__ cnt,
                                                    int* __restrict__ rowptr, int N) {
    __shared__ int sums[1024];
    int tid = threadIdx.x;
    int chunk = (N + 1023) >> 10;
    int start = tid * chunk;
    int end = min(start + chunk, N);
    int s = 0;
    for (int i = start; i < end; ++i) s += cnt[i];
    sums[tid] = s;
    __syncthreads();
    for (int off = 1; off < 1024; off <<= 1) {
        int t = (tid >= off) ? sums[tid - off] : 0;
        __syncthreads();
        sums[tid] += t;
        __syncthreads();
    }
    int run = (tid == 0) ? 0 : sums[tid - 1];
    for (int i = start; i < end; ++i) { rowptr[i] = run; run += cnt[i]; }
    if (tid == 1023) rowptr[N] = sums[1023];
}

__global__ __launch_bounds__(256) void scatter_kernel(const int* __restrict__ src,
                                                      const int* __restrict__ dst, int E,
                                                      const int* __restrict__ rowptr,
                                                      int* __restrict__ fill,
                                                      int* __restrict__ csr) {
    int e = blockIdx.x * 256 + threadIdx.x;
    if (e < E) {
        int d = dst[e];
        int pos = rowptr[d] + atomicAdd(&fill[d], 1);
        csr[pos] = src[e];
    }
}

// ---------------- GEMM (f32) with fused dinv row-scale ----------------
// HS[r][c] = dinv[r] * sum_k X[r][k] * W[k][c];  K = 256 fixed, C in {256,128}
// BM=128, BN=64, BK=16, 256 threads, 8x4 micro-tile per thread.
// Per k-step/thread: 32 FMA vs 3 ds_read_b128 -> FMA-issue-bound.

__global__ __launch_bounds__(256) void gemm_scale_kernel(const float* __restrict__ X,
                                                         const float* __restrict__ W,
                                                         const float* __restrict__ dinv,
                                                         float* __restrict__ HS,
                                                         int nRows, int C) {
    __shared__ float As[16][132];  // [k][m], pad stride 132 floats
    __shared__ float Bs[16][64];   // [k][n]

    int tid = threadIdx.x;
    int row0 = blockIdx.x << 7;   // BM=128
    int col0 = blockIdx.y << 6;   // BN=64

    int am = tid & 127, akq = tid >> 7;         // A loader: row am, quads {2*akq, 2*akq+1}
    int bk = tid >> 4, bc4 = (tid & 15) << 2;   // B loader
    int ty = tid >> 4, tx = tid & 15;           // compute: rows ty*8.., cols tx*4..

    int arow = row0 + am;
    bool aok = arow < nRows;
    const float* xrow = X + (size_t)(aok ? arow : (nRows - 1)) * IN_C;

    float acc[8][4] = {};

    for (int k0 = 0; k0 < IN_C; k0 += 16) {
        int q0 = akq << 1;
        float4 av0 = aok ? *(const float4*)(xrow + k0 + (q0 << 2))
                         : make_float4(0.f, 0.f, 0.f, 0.f);
        float4 av1 = aok ? *(const float4*)(xrow + k0 + ((q0 + 1) << 2))
                         : make_float4(0.f, 0.f, 0.f, 0.f);
        float4 bv = *(const float4*)(W + (size_t)(k0 + bk) * C + col0 + bc4);
        __syncthreads();
        As[(q0 << 2) + 0][am] = av0.x;
        As[(q0 << 2) + 1][am] = av0.y;
        As[(q0 << 2) + 2][am] = av0.z;
        As[(q0 << 2) + 3][am] = av0.w;
        As[(q0 << 2) + 4][am] = av1.x;
        As[(q0 << 2) + 5][am] = av1.y;
        As[(q0 << 2) + 6][am] = av1.z;
        As[(q0 << 2) + 7][am] = av1.w;
        *(float4*)(&Bs[bk][bc4]) = bv;
        __syncthreads();
#pragma unroll
        for (int k = 0; k < 16; ++k) {
            float4 a0 = *(const float4*)(&As[k][(ty << 3)]);
            float4 a1 = *(const float4*)(&As[k][(ty << 3) + 4]);
            float4 b = *(const float4*)(&Bs[k][tx << 2]);
#define FMA_ROW(i, s) \
            acc[i][0] += (s) * b.x; acc[i][1] += (s) * b.y; \
            acc[i][2] += (s) * b.z; acc[i][3] += (s) * b.w;
            FMA_ROW(0, a0.x) FMA_ROW(1, a0.y) FMA_ROW(2, a0.z) FMA_ROW(3, a0.w)
            FMA_ROW(4, a1.x) FMA_ROW(5, a1.y) FMA_ROW(6, a1.z) FMA_ROW(7, a1.w)
#undef FMA_ROW
        }
    }

#pragma unroll
    for (int i = 0; i < 8; ++i) {
        int row = row0 + (ty << 3) + i;
        if (row < nRows) {
            float s = dinv[row];
            float4 o = make_float4(acc[i][0] * s, acc[i][1] * s, acc[i][2] * s, acc[i][3] * s);
            *(float4*)(HS + (size_t)row * C + col0 + (tx << 2)) = o;
        }
    }
}

// ---------------- aggregation: OUT[v] = relu?(dinv[v]*(HS[v] + sum_{u->v} HS[u]) + b) ----------
// one wave (64 lanes) per node; lane owns C/64 contiguous channels.

template <int C, bool RELU>
__global__ __launch_bounds__(256) void aggregate_kernel(const float* __restrict__ HS,
                                                        const int* __restrict__ rowptr,
                                                        const int* __restrict__ csr,
                                                        const float* __restrict__ dinv,
                                                        const float* __restrict__ bias,
                                                        float* __restrict__ OUT, int N) {
    int gid = blockIdx.x * 256 + threadIdx.x;
    int v = gid >> 6;
    int lane = threadIdx.x & 63;
    if (v >= N) return;

    int beg = rowptr[v];
    int end = rowptr[v + 1];

    if constexpr (C == 256) {
        const size_t co = (size_t)(lane << 2);
        float4 acc = *(const float4*)(HS + (size_t)v * C + co);
        float4 acc2 = make_float4(0.f, 0.f, 0.f, 0.f);
        int j = beg;
        for (; j + 2 <= end; j += 2) {
            int u0 = csr[j], u1 = csr[j + 1];
            float4 a = *(const float4*)(HS + (size_t)u0 * C + co);
            float4 b = *(const float4*)(HS + (size_t)u1 * C + co);
            acc.x += a.x; acc.y += a.y; acc.z += a.z; acc.w += a.w;
            acc2.x += b.x; acc2.y += b.y; acc2.z += b.z; acc2.w += b.w;
        }
        if (j < end) {
            int u = csr[j];
            float4 a = *(const float4*)(HS + (size_t)u * C + co);
            acc.x += a.x; acc.y += a.y; acc.z += a.z; acc.w += a.w;
        }
        acc.x += acc2.x; acc.y += acc2.y; acc.z += acc2.z; acc.w += acc2.w;
        float s = dinv[v];
        float4 bb = *(const float4*)(bias + co);
        float4 o = make_float4(acc.x * s + bb.x, acc.y * s + bb.y,
                               acc.z * s + bb.z, acc.w * s + bb.w);
        if (RELU) {
            o.x = fmaxf(o.x, 0.f); o.y = fmaxf(o.y, 0.f);
            o.z = fmaxf(o.z, 0.f); o.w = fmaxf(o.w, 0.f);
        }
        *(float4*)(OUT + (size_t)v * C + co) = o;
    } else {  // C == 128
        const size_t co = (size_t)(lane << 1);
        float2 acc = *(const float2*)(HS + (size_t)v * C + co);
        float2 acc2 = make_float2(0.f, 0.f);
        int j = beg;
        for (; j + 2 <= end; j += 2) {
            int u0 = csr[j], u1 = csr[j + 1];
            float2 a = *(const float2*)(HS + (size_t)u0 * C + co);
            float2 b = *(const float2*)(HS + (size_t)u1 * C + co);
            acc.x += a.x; acc.y += a.y;
            acc2.x += b.x; acc2.y += b.y;
        }
        if (j < end) {
            int u = csr[j];
            float2 a = *(const float2*)(HS + (size_t)u * C + co);
            acc.x += a.x; acc.y += a.y;
        }
        acc.x += acc2.x; acc.y += acc2.y;
        float s = dinv[v];
        float2 bb = *(const float2*)(bias + co);
        float2 o = make_float2(acc.x * s + bb.x, acc.y * s + bb.y);
        if (RELU) { o.x = fmaxf(o.x, 0.f); o.y = fmaxf(o.y, 0.f); }
        *(float2*)(OUT + (size_t)v * C + co) = o;
    }
}

// ---------------- pooling ----------------

// batch is sorted: per-graph count via two binary searches. One block, 64 threads.
__global__ __launch_bounds__(64) void batch_count_kernel(const int* __restrict__ batch, int N,
                                                         int* __restrict__ gcnt) {
    int g = threadIdx.x;
    if (g >= NUM_GRAPHS) return;
    auto lb = [&](int key) {
        int lo = 0, hi = N;
        while (lo < hi) { int mid = (lo + hi) >> 1; if (batch[mid] < key) lo = mid + 1; else hi = mid; }
        return lo;
    };
    gcnt[g] = lb(g + 1) - lb(g);
}

// block = 128 threads (one per channel), each block scans a contiguous chunk of nodes.
__global__ __launch_bounds__(128) void pool_kernel(const float* __restrict__ H,
                                                   const int* __restrict__ batch,
                                                   float* __restrict__ gsum, int N) {
    const int NODES_PER_BLOCK = 256;
    int c = threadIdx.x;
    int start = blockIdx.x * NODES_PER_BLOCK;
    if (start >= N) return;
    int end = min(start + NODES_PER_BLOCK, N);
    float acc = 0.f;
    int cur = batch[start];
    for (int i = start; i < end; ++i) {
        int b = batch[i];
        if (b != cur) {
            atomicAdd(&gsum[cur * OUT_C + c], acc);
            acc = 0.f;
            cur = b;
        }
        acc += H[(size_t)i * OUT_C + c];
    }
    atomicAdd(&gsum[cur * OUT_C + c], acc);
}

__global__ __launch_bounds__(256) void finalize_kernel(const float* __restrict__ gsum,
                                                       const int* __restrict__ gcnt,
                                                       float* __restrict__ out) {
    int idx = blockIdx.x * 256 + threadIdx.x;
    if (idx < NUM_GRAPHS * OUT_C) {
        int g = idx >> 7;  // /OUT_C
        out[idx] = gsum[idx] / fmaxf((float)gcnt[g], 1.f);
    }
}

// ---------------- launch ----------------

extern "C" void kernel_launch(void* const* d_in, const int* in_sizes, int n_in,
                              void* d_out, int out_size, void* d_ws, size_t ws_size,
                              hipStream_t stream) {
    const float* x  = (const float*)d_in[0];
    const int* edge = (const int*)d_in[1];
    const int* batch = (const int*)d_in[2];
    const float* W1 = (const float*)d_in[3];
    const float* b1 = (const float*)d_in[4];
    const float* W2 = (const float*)d_in[5];
    const float* b2 = (const float*)d_in[6];
    const float* W3 = (const float*)d_in[7];
    const float* b3 = (const float*)d_in[8];

    const int N = in_sizes[0] / IN_C;
    const int E = in_sizes[1] / 2;
    const int* src = edge;
    const int* dst = edge + E;

    char* ws = (char*)d_ws;
    size_t off = 0;
    auto alloc = [&](size_t bytes) -> void* {
        void* p = ws + off;
        off += (bytes + 255) & ~(size_t)255;
        return p;
    };
    float* bufA   = (float*)alloc((size_t)N * HID_C * sizeof(float));
    float* bufB   = (float*)alloc((size_t)N * HID_C * sizeof(float));
    float* dinv   = (float*)alloc((size_t)N * sizeof(float));
    int*   cnt    = (int*)alloc((size_t)N * sizeof(int));
    int*   rowptr = (int*)alloc((size_t)(N + 1) * sizeof(int));
    int*   fill   = (int*)alloc((size_t)N * sizeof(int));
    int*   csr    = (int*)alloc((size_t)E * sizeof(int));
    float* gsum   = (float*)alloc((size_t)NUM_GRAPHS * OUT_C * sizeof(float));
    int*   gcnt   = (int*)alloc((size_t)NUM_GRAPHS * sizeof(int));

    hipMemsetAsync(cnt, 0, (size_t)N * sizeof(int), stream);
    hipMemsetAsync(fill, 0, (size_t)N * sizeof(int), stream);
    hipMemsetAsync(gsum, 0, (size_t)NUM_GRAPHS * OUT_C * sizeof(float), stream);

    int eb = (E + 255) / 256;
    int nb = (N + 255) / 256;
    int mt = (N + 127) / 128;       // BM=128
    int ab = (N * 64 + 255) / 256;  // aggregate: one wave per node

    count_deg_kernel<<<eb, 256, 0, stream>>>(dst, E, cnt);
    dinv_kernel<<<nb, 256, 0, stream>>>(cnt, dinv, N);
    scan_kernel<<<1, 1024, 0, stream>>>(cnt, rowptr, N);
    scatter_kernel<<<eb, 256, 0, stream>>>(src, dst, E, rowptr, fill, csr);

    // layer 1: x @ W1 -> bufA (scaled), aggregate -> bufB (+b1, relu)
    gemm_scale_kernel<<<dim3(mt, HID_C / 64), 256, 0, stream>>>(x, W1, dinv, bufA, N, HID_C);
    aggregate_kernel<256, true><<<ab, 256, 0, stream>>>(bufA, rowptr, csr, dinv, b1, bufB, N);

    // layer 2
    gemm_scale_kernel<<<dim3(mt, HID_C / 64), 256, 0, stream>>>(bufB, W2, dinv, bufA, N, HID_C);
    aggregate_kernel<256, true><<<ab, 256, 0, stream>>>(bufA, rowptr, csr, dinv, b2, bufB, N);

    // layer 3 (C=128, no relu)
    gemm_scale_kernel<<<dim3(mt, OUT_C / 64), 256, 0, stream>>>(bufB, W3, dinv, bufA, N, OUT_C);
    aggregate_kernel<128, false><<<ab, 256, 0, stream>>>(bufA, rowptr, csr, dinv, b3, bufB, N);

    // mean pool
    batch_count_kernel<<<1, 64, 0, stream>>>(batch, N, gcnt);
    pool_kernel<<<(N + 255) / 256, 128, 0, stream>>>(bufB, batch, gsum, N);
    finalize_kernel<<<(NUM_GRAPHS * OUT_C + 255) / 256, 256, 0, stream>>>(gsum, gcnt, (float*)d_out);
}

// Round 3
// 1318.203 us; speedup vs baseline: 1.9849x; 1.6031x over previous
//
#include <hip/hip_runtime.h>

#define IN_C 256
#define HID_C 256
#define OUT_C 128
#define NUM_GRAPHS 64

typedef _Float16 half2v __attribute__((ext_vector_type(2)));
typedef _Float16 half4v __attribute__((ext_vector_type(4)));
typedef _Float16 half8v __attribute__((ext_vector_type(8)));
typedef float f32x2 __attribute__((ext_vector_type(2)));
typedef float f32x4 __attribute__((ext_vector_type(4)));

// ---------------- degree / CSR build ----------------

__global__ __launch_bounds__(256) void count_deg_kernel(const int* __restrict__ dst, int E,
                                                        int* __restrict__ cnt) {
    int e = blockIdx.x * 256 + threadIdx.x;
    if (e < E) atomicAdd(&cnt[dst[e]], 1);
}

__global__ __launch_bounds__(256) void dinv_kernel(const int* __restrict__ cnt,
                                                   float* __restrict__ dinv, int N) {
    int i = blockIdx.x * 256 + threadIdx.x;
    if (i < N) dinv[i] = rsqrtf((float)(cnt[i] + 1));  // +1 self loop
}

__global__ __launch_bounds__(1024) void scan_kernel(const int* __restrict__ cnt,
                                                    int* __restrict__ rowptr, int N) {
    __shared__ int sums[1024];
    int tid = threadIdx.x;
    int chunk = (N + 1023) >> 10;
    int start = tid * chunk;
    int end = min(start + chunk, N);
    int s = 0;
    for (int i = start; i < end; ++i) s += cnt[i];
    sums[tid] = s;
    __syncthreads();
    for (int off = 1; off < 1024; off <<= 1) {
        int t = (tid >= off) ? sums[tid - off] : 0;
        __syncthreads();
        sums[tid] += t;
        __syncthreads();
    }
    int run = (tid == 0) ? 0 : sums[tid - 1];
    for (int i = start; i < end; ++i) { rowptr[i] = run; run += cnt[i]; }
    if (tid == 1023) rowptr[N] = sums[1023];
}

__global__ __launch_bounds__(256) void scatter_kernel(const int* __restrict__ src,
                                                      const int* __restrict__ dst, int E,
                                                      const int* __restrict__ rowptr,
                                                      int* __restrict__ fill,
                                                      int* __restrict__ csr) {
    int e = blockIdx.x * 256 + threadIdx.x;
    if (e < E) {
        int d = dst[e];
        int pos = rowptr[d] + atomicAdd(&fill[d], 1);
        csr[pos] = src[e];
    }
}

// ---------------- dtype prep ----------------

__global__ __launch_bounds__(256) void f32_to_f16_kernel(const float* __restrict__ in,
                                                         _Float16* __restrict__ out, int n4) {
    int i = blockIdx.x * 256 + threadIdx.x;
    if (i < n4) {
        f32x4 v = *(const f32x4*)(in + (size_t)i * 4);
        *(half4v*)(out + (size_t)i * 4) = __builtin_convertvector(v, half4v);
    }
}

// W [K][C] f32  ->  Wt [C][K] f16
__global__ __launch_bounds__(256) void wt_f16_kernel(const float* __restrict__ W,
                                                     _Float16* __restrict__ Wt, int K, int C) {
    int idx = blockIdx.x * 256 + threadIdx.x;
    if (idx < K * C) {
        int k = idx / C, c = idx - k * C;
        Wt[c * K + k] = (_Float16)W[idx];
    }
}

// ---------------- MFMA f16 GEMM with fused dinv row-scale ----------------
// HS[r][c] = dinv[r] * sum_k A[r][k] * Wt[c][k];  K=256, BM=64, BN=C, BK=32.
// 256 threads = 4 waves, wave owns 64 x (BN/4) quadrant via 16x16x32 MFMA.

template <int BN>
__global__ __launch_bounds__(256) void gemm_f16_kernel(const _Float16* __restrict__ A,
                                                       const _Float16* __restrict__ Bt,
                                                       const float* __restrict__ dinv,
                                                       _Float16* __restrict__ HS,
                                                       int nRows) {
    constexpr int K = 256;
    constexpr int BK = 32;
    constexpr int LDR = 40;      // f16 per LDS row (80 B stride -> <=2-way bank alias)
    constexpr int NF = BN / 64;  // n-fragments per wave

    __shared__ __align__(16) _Float16 Al[64 * LDR];
    __shared__ __align__(16) _Float16 Bl[BN * LDR];

    const int tid = threadIdx.x;
    const int wave = tid >> 6;
    const int lane = tid & 63;
    const int row0 = blockIdx.x << 6;

    const int ar = tid >> 2;          // staging row 0..63
    const int ac = (tid & 3) << 3;    // staging f16 col {0,8,16,24}
    const int arow = min(row0 + ar, nRows - 1);

    const int fr = lane & 15;         // A-row / B-col within fragment
    const int k8 = lane >> 4;         // k-chunk 0..3

    f32x4 acc[4][NF] = {};

    for (int k0 = 0; k0 < K; k0 += BK) {
        half8v av = *(const half8v*)(A + (size_t)arow * K + k0 + ac);
        half8v bv[NF];
#pragma unroll
        for (int j = 0; j < NF; ++j)
            bv[j] = *(const half8v*)(Bt + (size_t)(ar + 64 * j) * K + k0 + ac);
        __syncthreads();
        *(half8v*)(Al + ar * LDR + ac) = av;
#pragma unroll
        for (int j = 0; j < NF; ++j)
            *(half8v*)(Bl + (ar + 64 * j) * LDR + ac) = bv[j];
        __syncthreads();

        half8v af[4], bf[NF];
#pragma unroll
        for (int m = 0; m < 4; ++m)
            af[m] = *(const half8v*)(Al + (m * 16 + fr) * LDR + k8 * 8);
#pragma unroll
        for (int n = 0; n < NF; ++n)
            bf[n] = *(const half8v*)(Bl + (wave * (BN / 4) + n * 16 + fr) * LDR + k8 * 8);
#pragma unroll
        for (int m = 0; m < 4; ++m)
#pragma unroll
            for (int n = 0; n < NF; ++n)
                acc[m][n] = __builtin_amdgcn_mfma_f32_16x16x32_f16(af[m], bf[n], acc[m][n], 0, 0, 0);
    }

    // D mapping: col = lane&15, row = (lane>>4)*4 + r
#pragma unroll
    for (int m = 0; m < 4; ++m) {
        int rb = row0 + m * 16 + k8 * 4;
        float s[4];
#pragma unroll
        for (int r = 0; r < 4; ++r) s[r] = (rb + r < nRows) ? dinv[rb + r] : 0.f;
#pragma unroll
        for (int n = 0; n < NF; ++n) {
            int col = wave * (BN / 4) + n * 16 + fr;
#pragma unroll
            for (int r = 0; r < 4; ++r) {
                int row = rb + r;
                if (row < nRows)
                    HS[(size_t)row * BN + col] = (_Float16)(acc[m][n][r] * s[r]);
            }
        }
    }
}

// ---------------- aggregation ----------------
// OUT[v] = relu(dinv[v]*(HS[v] + sum_{u->v} HS[u]) + b); one wave per node.

__global__ __launch_bounds__(256) void agg256_f16(const _Float16* __restrict__ HS,
                                                  const int* __restrict__ rowptr,
                                                  const int* __restrict__ csr,
                                                  const float* __restrict__ dinv,
                                                  const float* __restrict__ bias,
                                                  _Float16* __restrict__ OUT, int N) {
    int gid = blockIdx.x * 256 + threadIdx.x;
    int v = gid >> 6;
    if (v >= N) return;
    int lane = threadIdx.x & 63;
    int co = lane << 2;
    const _Float16* base = HS + co;

    f32x4 acc = __builtin_convertvector(*(const half4v*)(base + (size_t)v * 256), f32x4);
    f32x4 acc2 = {};
    int j = rowptr[v], end = rowptr[v + 1];
    for (; j + 2 <= end; j += 2) {
        int u0 = csr[j], u1 = csr[j + 1];
        acc  += __builtin_convertvector(*(const half4v*)(base + (size_t)u0 * 256), f32x4);
        acc2 += __builtin_convertvector(*(const half4v*)(base + (size_t)u1 * 256), f32x4);
    }
    if (j < end)
        acc += __builtin_convertvector(*(const half4v*)(base + (size_t)csr[j] * 256), f32x4);
    acc += acc2;

    float s = dinv[v];
    f32x4 bb = *(const f32x4*)(bias + co);
    f32x4 o = acc * s + bb;
    o.x = fmaxf(o.x, 0.f); o.y = fmaxf(o.y, 0.f);
    o.z = fmaxf(o.z, 0.f); o.w = fmaxf(o.w, 0.f);
    *(half4v*)(OUT + (size_t)v * 256 + co) = __builtin_convertvector(o, half4v);
}

// final layer: C=128, no relu, f32 output for pooling
__global__ __launch_bounds__(256) void agg128_f16(const _Float16* __restrict__ HS,
                                                  const int* __restrict__ rowptr,
                                                  const int* __restrict__ csr,
                                                  const float* __restrict__ dinv,
                                                  const float* __restrict__ bias,
                                                  float* __restrict__ OUT, int N) {
    int gid = blockIdx.x * 256 + threadIdx.x;
    int v = gid >> 6;
    if (v >= N) return;
    int lane = threadIdx.x & 63;
    int co = lane << 1;
    const _Float16* base = HS + co;

    f32x2 acc = __builtin_convertvector(*(const half2v*)(base + (size_t)v * 128), f32x2);
    f32x2 acc2 = {};
    int j = rowptr[v], end = rowptr[v + 1];
    for (; j + 2 <= end; j += 2) {
        int u0 = csr[j], u1 = csr[j + 1];
        acc  += __builtin_convertvector(*(const half2v*)(base + (size_t)u0 * 128), f32x2);
        acc2 += __builtin_convertvector(*(const half2v*)(base + (size_t)u1 * 128), f32x2);
    }
    if (j < end)
        acc += __builtin_convertvector(*(const half2v*)(base + (size_t)csr[j] * 128), f32x2);
    acc += acc2;

    float s = dinv[v];
    f32x2 bb = *(const f32x2*)(bias + co);
    f32x2 o = acc * s + bb;
    *(f32x2*)(OUT + (size_t)v * 128 + co) = o;
}

// ---------------- pooling ----------------

__global__ __launch_bounds__(64) void batch_count_kernel(const int* __restrict__ batch, int N,
                                                         int* __restrict__ gcnt) {
    int g = threadIdx.x;
    if (g >= NUM_GRAPHS) return;
    auto lb = [&](int key) {
        int lo = 0, hi = N;
        while (lo < hi) { int mid = (lo + hi) >> 1; if (batch[mid] < key) lo = mid + 1; else hi = mid; }
        return lo;
    };
    gcnt[g] = lb(g + 1) - lb(g);
}

__global__ __launch_bounds__(128) void pool_kernel(const float* __restrict__ H,
                                                   const int* __restrict__ batch,
                                                   float* __restrict__ gsum, int N) {
    const int NODES_PER_BLOCK = 256;
    int c = threadIdx.x;
    int start = blockIdx.x * NODES_PER_BLOCK;
    if (start >= N) return;
    int end = min(start + NODES_PER_BLOCK, N);
    float acc = 0.f;
    int cur = batch[start];
    for (int i = start; i < end; ++i) {
        int b = batch[i];
        if (b != cur) {
            atomicAdd(&gsum[cur * OUT_C + c], acc);
            acc = 0.f;
            cur = b;
        }
        acc += H[(size_t)i * OUT_C + c];
    }
    atomicAdd(&gsum[cur * OUT_C + c], acc);
}

__global__ __launch_bounds__(256) void finalize_kernel(const float* __restrict__ gsum,
                                                       const int* __restrict__ gcnt,
                                                       float* __restrict__ out) {
    int idx = blockIdx.x * 256 + threadIdx.x;
    if (idx < NUM_GRAPHS * OUT_C) {
        int g = idx >> 7;
        out[idx] = gsum[idx] / fmaxf((float)gcnt[g], 1.f);
    }
}

// ---------------- launch ----------------

extern "C" void kernel_launch(void* const* d_in, const int* in_sizes, int n_in,
                              void* d_out, int out_size, void* d_ws, size_t ws_size,
                              hipStream_t stream) {
    const float* x  = (const float*)d_in[0];
    const int* edge = (const int*)d_in[1];
    const int* batch = (const int*)d_in[2];
    const float* W1 = (const float*)d_in[3];
    const float* b1 = (const float*)d_in[4];
    const float* W2 = (const float*)d_in[5];
    const float* b2 = (const float*)d_in[6];
    const float* W3 = (const float*)d_in[7];
    const float* b3 = (const float*)d_in[8];

    const int N = in_sizes[0] / IN_C;
    const int E = in_sizes[1] / 2;
    const int* src = edge;
    const int* dst = edge + E;

    char* ws = (char*)d_ws;
    size_t off = 0;
    auto alloc = [&](size_t bytes) -> void* {
        void* p = ws + off;
        off += (bytes + 255) & ~(size_t)255;
        return p;
    };
    _Float16* hA   = (_Float16*)alloc((size_t)N * HID_C * sizeof(_Float16));  // layer input
    _Float16* hS   = (_Float16*)alloc((size_t)N * HID_C * sizeof(_Float16));  // gemm out / gather src
    float*    h3   = (float*)alloc((size_t)N * OUT_C * sizeof(float));        // final node feats
    _Float16* wt1  = (_Float16*)alloc((size_t)IN_C * HID_C * sizeof(_Float16));
    _Float16* wt2  = (_Float16*)alloc((size_t)HID_C * HID_C * sizeof(_Float16));
    _Float16* wt3  = (_Float16*)alloc((size_t)HID_C * OUT_C * sizeof(_Float16));
    float* dinv    = (float*)alloc((size_t)N * sizeof(float));
    int*   cnt     = (int*)alloc((size_t)N * sizeof(int));
    int*   rowptr  = (int*)alloc((size_t)(N + 1) * sizeof(int));
    int*   fill    = (int*)alloc((size_t)N * sizeof(int));
    int*   csr     = (int*)alloc((size_t)E * sizeof(int));
    float* gsum    = (float*)alloc((size_t)NUM_GRAPHS * OUT_C * sizeof(float));
    int*   gcnt    = (int*)alloc((size_t)NUM_GRAPHS * sizeof(int));

    hipMemsetAsync(cnt, 0, (size_t)N * sizeof(int), stream);
    hipMemsetAsync(fill, 0, (size_t)N * sizeof(int), stream);
    hipMemsetAsync(gsum, 0, (size_t)NUM_GRAPHS * OUT_C * sizeof(float), stream);

    int eb = (E + 255) / 256;
    int nb = (N + 255) / 256;
    int mt = (N + 63) / 64;         // gemm blocks (BM=64)
    int ab = (N * 64 + 255) / 256;  // aggregate: one wave per node

    count_deg_kernel<<<eb, 256, 0, stream>>>(dst, E, cnt);
    dinv_kernel<<<nb, 256, 0, stream>>>(cnt, dinv, N);
    scan_kernel<<<1, 1024, 0, stream>>>(cnt, rowptr, N);
    scatter_kernel<<<eb, 256, 0, stream>>>(src, dst, E, rowptr, fill, csr);

    // dtype prep
    f32_to_f16_kernel<<<(N * IN_C / 4 + 255) / 256, 256, 0, stream>>>(x, hA, N * IN_C / 4);
    wt_f16_kernel<<<(IN_C * HID_C + 255) / 256, 256, 0, stream>>>(W1, wt1, IN_C, HID_C);
    wt_f16_kernel<<<(HID_C * HID_C + 255) / 256, 256, 0, stream>>>(W2, wt2, HID_C, HID_C);
    wt_f16_kernel<<<(HID_C * OUT_C + 255) / 256, 256, 0, stream>>>(W3, wt3, HID_C, OUT_C);

    // layer 1
    gemm_f16_kernel<256><<<mt, 256, 0, stream>>>(hA, wt1, dinv, hS, N);
    agg256_f16<<<ab, 256, 0, stream>>>(hS, rowptr, csr, dinv, b1, hA, N);
    // layer 2
    gemm_f16_kernel<256><<<mt, 256, 0, stream>>>(hA, wt2, dinv, hS, N);
    agg256_f16<<<ab, 256, 0, stream>>>(hS, rowptr, csr, dinv, b2, hA, N);
    // layer 3 (C=128, f32 out)
    gemm_f16_kernel<128><<<mt, 256, 0, stream>>>(hA, wt3, dinv, hS, N);
    agg128_f16<<<ab, 256, 0, stream>>>(hS, rowptr, csr, dinv, b3, h3, N);

    // mean pool
    batch_count_kernel<<<1, 64, 0, stream>>>(batch, N, gcnt);
    pool_kernel<<<(N + 255) / 256, 128, 0, stream>>>(h3, batch, gsum, N);
    finalize_kernel<<<(NUM_GRAPHS * OUT_C + 255) / 256, 256, 0, stream>>>(gsum, gcnt, (float*)d_out);
}

// Round 4
// 1261.716 us; speedup vs baseline: 2.0738x; 1.0448x over previous
//
#include <hip/hip_runtime.h>

#define IN_C 256
#define HID_C 256
#define OUT_C 128
#define NUM_GRAPHS 64

typedef _Float16 half2v __attribute__((ext_vector_type(2)));
typedef _Float16 half4v __attribute__((ext_vector_type(4)));
typedef _Float16 half8v __attribute__((ext_vector_type(8)));
typedef float f32x2 __attribute__((ext_vector_type(2)));
typedef float f32x4 __attribute__((ext_vector_type(4)));
typedef float f32x8 __attribute__((ext_vector_type(8)));

// ---------------- degree / CSR build ----------------

__global__ __launch_bounds__(256) void count_deg_kernel(const int* __restrict__ dst, int E,
                                                        int* __restrict__ cnt) {
    int e = blockIdx.x * 256 + threadIdx.x;
    if (e < E) atomicAdd(&cnt[dst[e]], 1);
}

__global__ __launch_bounds__(256) void dinv_kernel(const int* __restrict__ cnt,
                                                   float* __restrict__ dinv, int N) {
    int i = blockIdx.x * 256 + threadIdx.x;
    if (i < N) dinv[i] = rsqrtf((float)(cnt[i] + 1));  // +1 self loop
}

__global__ __launch_bounds__(1024) void scan_kernel(const int* __restrict__ cnt,
                                                    int* __restrict__ rowptr, int N) {
    __shared__ int sums[1024];
    int tid = threadIdx.x;
    int chunk = (N + 1023) >> 10;
    int start = tid * chunk;
    int end = min(start + chunk, N);
    int s = 0;
    for (int i = start; i < end; ++i) s += cnt[i];
    sums[tid] = s;
    __syncthreads();
    for (int off = 1; off < 1024; off <<= 1) {
        int t = (tid >= off) ? sums[tid - off] : 0;
        __syncthreads();
        sums[tid] += t;
        __syncthreads();
    }
    int run = (tid == 0) ? 0 : sums[tid - 1];
    for (int i = start; i < end; ++i) { rowptr[i] = run; run += cnt[i]; }
    if (tid == 1023) rowptr[N] = sums[1023];
}

__global__ __launch_bounds__(256) void scatter_kernel(const int* __restrict__ src,
                                                      const int* __restrict__ dst, int E,
                                                      const int* __restrict__ rowptr,
                                                      int* __restrict__ fill,
                                                      int* __restrict__ csr) {
    int e = blockIdx.x * 256 + threadIdx.x;
    if (e < E) {
        int d = dst[e];
        int pos = rowptr[d] + atomicAdd(&fill[d], 1);
        csr[pos] = src[e];
    }
}

// ---------------- dtype prep ----------------

__global__ __launch_bounds__(256) void f32_to_f16_kernel(const float* __restrict__ in,
                                                         _Float16* __restrict__ out, int n4) {
    int i = blockIdx.x * 256 + threadIdx.x;
    if (i < n4) {
        f32x4 v = *(const f32x4*)(in + (size_t)i * 4);
        *(half4v*)(out + (size_t)i * 4) = __builtin_convertvector(v, half4v);
    }
}

// W [K][C] f32  ->  Wt [C][K] f16
__global__ __launch_bounds__(256) void wt_f16_kernel(const float* __restrict__ W,
                                                     _Float16* __restrict__ Wt, int K, int C) {
    int idx = blockIdx.x * 256 + threadIdx.x;
    if (idx < K * C) {
        int k = idx / C, c = idx - k * C;
        Wt[c * K + k] = (_Float16)W[idx];
    }
}

// ---------------- MFMA f16 GEMM with fused dinv row-scale ----------------

template <int BN>
__global__ __launch_bounds__(256) void gemm_f16_kernel(const _Float16* __restrict__ A,
                                                       const _Float16* __restrict__ Bt,
                                                       const float* __restrict__ dinv,
                                                       _Float16* __restrict__ HS,
                                                       int nRows) {
    constexpr int K = 256;
    constexpr int BK = 32;
    constexpr int LDR = 40;
    constexpr int NF = BN / 64;

    __shared__ __align__(16) _Float16 Al[64 * LDR];
    __shared__ __align__(16) _Float16 Bl[BN * LDR];

    const int tid = threadIdx.x;
    const int wave = tid >> 6;
    const int lane = tid & 63;
    const int row0 = blockIdx.x << 6;

    const int ar = tid >> 2;
    const int ac = (tid & 3) << 3;
    const int arow = min(row0 + ar, nRows - 1);

    const int fr = lane & 15;
    const int k8 = lane >> 4;

    f32x4 acc[4][NF] = {};

    for (int k0 = 0; k0 < K; k0 += BK) {
        half8v av = *(const half8v*)(A + (size_t)arow * K + k0 + ac);
        half8v bv[NF];
#pragma unroll
        for (int j = 0; j < NF; ++j)
            bv[j] = *(const half8v*)(Bt + (size_t)(ar + 64 * j) * K + k0 + ac);
        __syncthreads();
        *(half8v*)(Al + ar * LDR + ac) = av;
#pragma unroll
        for (int j = 0; j < NF; ++j)
            *(half8v*)(Bl + (ar + 64 * j) * LDR + ac) = bv[j];
        __syncthreads();

        half8v af[4], bf[NF];
#pragma unroll
        for (int m = 0; m < 4; ++m)
            af[m] = *(const half8v*)(Al + (m * 16 + fr) * LDR + k8 * 8);
#pragma unroll
        for (int n = 0; n < NF; ++n)
            bf[n] = *(const half8v*)(Bl + (wave * (BN / 4) + n * 16 + fr) * LDR + k8 * 8);
#pragma unroll
        for (int m = 0; m < 4; ++m)
#pragma unroll
            for (int n = 0; n < NF; ++n)
                acc[m][n] = __builtin_amdgcn_mfma_f32_16x16x32_f16(af[m], bf[n], acc[m][n], 0, 0, 0);
    }

#pragma unroll
    for (int m = 0; m < 4; ++m) {
        int rb = row0 + m * 16 + k8 * 4;
        float s[4];
#pragma unroll
        for (int r = 0; r < 4; ++r) s[r] = (rb + r < nRows) ? dinv[rb + r] : 0.f;
#pragma unroll
        for (int n = 0; n < NF; ++n) {
            int col = wave * (BN / 4) + n * 16 + fr;
#pragma unroll
            for (int r = 0; r < 4; ++r) {
                int row = rb + r;
                if (row < nRows)
                    HS[(size_t)row * BN + col] = (_Float16)(acc[m][n][r] * s[r]);
            }
        }
    }
}

// ---------------- aggregation ----------------
// OUT[v] = relu(dinv[v]*(HS[v] + sum_{u->v} HS[u]) + b)
// C=256: 2 nodes/wave, 32 lanes x 16B per row; 4 row-gathers in flight.

__global__ __launch_bounds__(256) void agg256_f16(const _Float16* __restrict__ HS,
                                                  const int* __restrict__ rowptr,
                                                  const int* __restrict__ csr,
                                                  const float* __restrict__ dinv,
                                                  const float* __restrict__ bias,
                                                  _Float16* __restrict__ OUT, int N) {
    int wid = (blockIdx.x << 2) + (threadIdx.x >> 6);
    int lane = threadIdx.x & 63;
    int v = (wid << 1) + (lane >> 5);
    if (v >= N) return;
    int co = (lane & 31) << 3;  // f16 index; 16B per lane
    const _Float16* base = HS + co;

    f32x8 acc = __builtin_convertvector(*(const half8v*)(base + (size_t)v * 256), f32x8);
    f32x8 acc2 = {};
    int j = rowptr[v], end = rowptr[v + 1];
    for (; j + 2 <= end; j += 2) {
        int u0 = csr[j], u1 = csr[j + 1];
        half8v a = *(const half8v*)(base + (size_t)u0 * 256);
        half8v b = *(const half8v*)(base + (size_t)u1 * 256);
        acc  += __builtin_convertvector(a, f32x8);
        acc2 += __builtin_convertvector(b, f32x8);
    }
    if (j < end)
        acc += __builtin_convertvector(*(const half8v*)(base + (size_t)csr[j] * 256), f32x8);
    acc += acc2;

    float s = dinv[v];
    f32x4 b0 = *(const f32x4*)(bias + co);
    f32x4 b1 = *(const f32x4*)(bias + co + 4);
    f32x8 bb;
    bb.s0 = b0.x; bb.s1 = b0.y; bb.s2 = b0.z; bb.s3 = b0.w;
    bb.s4 = b1.x; bb.s5 = b1.y; bb.s6 = b1.z; bb.s7 = b1.w;
    f32x8 o = acc * s + bb;
#pragma unroll
    for (int t = 0; t < 8; ++t) o[t] = fmaxf(o[t], 0.f);
    *(half8v*)(OUT + (size_t)v * 256 + co) = __builtin_convertvector(o, half8v);
}

// C=128: 4 nodes/wave, 16 lanes x 16B per row; f32 output, no relu.

__global__ __launch_bounds__(256) void agg128_f16(const _Float16* __restrict__ HS,
                                                  const int* __restrict__ rowptr,
                                                  const int* __restrict__ csr,
                                                  const float* __restrict__ dinv,
                                                  const float* __restrict__ bias,
                                                  float* __restrict__ OUT, int N) {
    int wid = (blockIdx.x << 2) + (threadIdx.x >> 6);
    int lane = threadIdx.x & 63;
    int v = (wid << 2) + (lane >> 4);
    if (v >= N) return;
    int co = (lane & 15) << 3;  // f16 index; 16B per lane
    const _Float16* base = HS + co;

    f32x8 acc = __builtin_convertvector(*(const half8v*)(base + (size_t)v * 128), f32x8);
    f32x8 acc2 = {};
    int j = rowptr[v], end = rowptr[v + 1];
    for (; j + 2 <= end; j += 2) {
        int u0 = csr[j], u1 = csr[j + 1];
        half8v a = *(const half8v*)(base + (size_t)u0 * 128);
        half8v b = *(const half8v*)(base + (size_t)u1 * 128);
        acc  += __builtin_convertvector(a, f32x8);
        acc2 += __builtin_convertvector(b, f32x8);
    }
    if (j < end)
        acc += __builtin_convertvector(*(const half8v*)(base + (size_t)csr[j] * 128), f32x8);
    acc += acc2;

    float s = dinv[v];
    f32x4 b0 = *(const f32x4*)(bias + co);
    f32x4 b1 = *(const f32x4*)(bias + co + 4);
    f32x8 o;
    o.s0 = acc.s0 * s + b0.x; o.s1 = acc.s1 * s + b0.y;
    o.s2 = acc.s2 * s + b0.z; o.s3 = acc.s3 * s + b0.w;
    o.s4 = acc.s4 * s + b1.x; o.s5 = acc.s5 * s + b1.y;
    o.s6 = acc.s6 * s + b1.z; o.s7 = acc.s7 * s + b1.w;
    float* op = OUT + (size_t)v * 128 + co;
    f32x4 lo, hi;
    lo.x = o.s0; lo.y = o.s1; lo.z = o.s2; lo.w = o.s3;
    hi.x = o.s4; hi.y = o.s5; hi.z = o.s6; hi.w = o.s7;
    *(f32x4*)(op) = lo;
    *(f32x4*)(op + 4) = hi;
}

// ---------------- pooling ----------------

__global__ __launch_bounds__(64) void batch_count_kernel(const int* __restrict__ batch, int N,
                                                         int* __restrict__ gcnt) {
    int g = threadIdx.x;
    if (g >= NUM_GRAPHS) return;
    auto lb = [&](int key) {
        int lo = 0, hi = N;
        while (lo < hi) { int mid = (lo + hi) >> 1; if (batch[mid] < key) lo = mid + 1; else hi = mid; }
        return lo;
    };
    gcnt[g] = lb(g + 1) - lb(g);
}

__global__ __launch_bounds__(128) void pool_kernel(const float* __restrict__ H,
                                                   const int* __restrict__ batch,
                                                   float* __restrict__ gsum, int N) {
    const int NODES_PER_BLOCK = 256;
    int c = threadIdx.x;
    int start = blockIdx.x * NODES_PER_BLOCK;
    if (start >= N) return;
    int end = min(start + NODES_PER_BLOCK, N);
    float acc = 0.f;
    int cur = batch[start];
    for (int i = start; i < end; ++i) {
        int b = batch[i];
        if (b != cur) {
            atomicAdd(&gsum[cur * OUT_C + c], acc);
            acc = 0.f;
            cur = b;
        }
        acc += H[(size_t)i * OUT_C + c];
    }
    atomicAdd(&gsum[cur * OUT_C + c], acc);
}

__global__ __launch_bounds__(256) void finalize_kernel(const float* __restrict__ gsum,
                                                       const int* __restrict__ gcnt,
                                                       float* __restrict__ out) {
    int idx = blockIdx.x * 256 + threadIdx.x;
    if (idx < NUM_GRAPHS * OUT_C) {
        int g = idx >> 7;
        out[idx] = gsum[idx] / fmaxf((float)gcnt[g], 1.f);
    }
}

// ---------------- launch ----------------

extern "C" void kernel_launch(void* const* d_in, const int* in_sizes, int n_in,
                              void* d_out, int out_size, void* d_ws, size_t ws_size,
                              hipStream_t stream) {
    const float* x  = (const float*)d_in[0];
    const int* edge = (const int*)d_in[1];
    const int* batch = (const int*)d_in[2];
    const float* W1 = (const float*)d_in[3];
    const float* b1 = (const float*)d_in[4];
    const float* W2 = (const float*)d_in[5];
    const float* b2 = (const float*)d_in[6];
    const float* W3 = (const float*)d_in[7];
    const float* b3 = (const float*)d_in[8];

    const int N = in_sizes[0] / IN_C;
    const int E = in_sizes[1] / 2;
    const int* src = edge;
    const int* dst = edge + E;

    char* ws = (char*)d_ws;
    size_t off = 0;
    auto alloc = [&](size_t bytes) -> void* {
        void* p = ws + off;
        off += (bytes + 255) & ~(size_t)255;
        return p;
    };
    _Float16* hA   = (_Float16*)alloc((size_t)N * HID_C * sizeof(_Float16));
    _Float16* hS   = (_Float16*)alloc((size_t)N * HID_C * sizeof(_Float16));
    float*    h3   = (float*)alloc((size_t)N * OUT_C * sizeof(float));
    _Float16* wt1  = (_Float16*)alloc((size_t)IN_C * HID_C * sizeof(_Float16));
    _Float16* wt2  = (_Float16*)alloc((size_t)HID_C * HID_C * sizeof(_Float16));
    _Float16* wt3  = (_Float16*)alloc((size_t)HID_C * OUT_C * sizeof(_Float16));
    float* dinv    = (float*)alloc((size_t)N * sizeof(float));
    int*   cnt     = (int*)alloc((size_t)N * sizeof(int));
    int*   rowptr  = (int*)alloc((size_t)(N + 1) * sizeof(int));
    int*   fill    = (int*)alloc((size_t)N * sizeof(int));
    int*   csr     = (int*)alloc((size_t)E * sizeof(int));
    float* gsum    = (float*)alloc((size_t)NUM_GRAPHS * OUT_C * sizeof(float));
    int*   gcnt    = (int*)alloc((size_t)NUM_GRAPHS * sizeof(int));

    hipMemsetAsync(cnt, 0, (size_t)N * sizeof(int), stream);
    hipMemsetAsync(fill, 0, (size_t)N * sizeof(int), stream);
    hipMemsetAsync(gsum, 0, (size_t)NUM_GRAPHS * OUT_C * sizeof(float), stream);

    int eb = (E + 255) / 256;
    int nb = (N + 255) / 256;
    int mt = (N + 63) / 64;
    int ab256 = ((N + 1) / 2 + 3) / 4;  // 2 nodes/wave, 4 waves/block
    int ab128 = ((N + 3) / 4 + 3) / 4;  // 4 nodes/wave, 4 waves/block

    count_deg_kernel<<<eb, 256, 0, stream>>>(dst, E, cnt);
    dinv_kernel<<<nb, 256, 0, stream>>>(cnt, dinv, N);
    scan_kernel<<<1, 1024, 0, stream>>>(cnt, rowptr, N);
    scatter_kernel<<<eb, 256, 0, stream>>>(src, dst, E, rowptr, fill, csr);

    f32_to_f16_kernel<<<(N * IN_C / 4 + 255) / 256, 256, 0, stream>>>(x, hA, N * IN_C / 4);
    wt_f16_kernel<<<(IN_C * HID_C + 255) / 256, 256, 0, stream>>>(W1, wt1, IN_C, HID_C);
    wt_f16_kernel<<<(HID_C * HID_C + 255) / 256, 256, 0, stream>>>(W2, wt2, HID_C, HID_C);
    wt_f16_kernel<<<(HID_C * OUT_C + 255) / 256, 256, 0, stream>>>(W3, wt3, HID_C, OUT_C);

    // layer 1
    gemm_f16_kernel<256><<<mt, 256, 0, stream>>>(hA, wt1, dinv, hS, N);
    agg256_f16<<<ab256, 256, 0, stream>>>(hS, rowptr, csr, dinv, b1, hA, N);
    // layer 2
    gemm_f16_kernel<256><<<mt, 256, 0, stream>>>(hA, wt2, dinv, hS, N);
    agg256_f16<<<ab256, 256, 0, stream>>>(hS, rowptr, csr, dinv, b2, hA, N);
    // layer 3
    gemm_f16_kernel<128><<<mt, 256, 0, stream>>>(hA, wt3, dinv, hS, N);
    agg128_f16<<<ab128, 256, 0, stream>>>(hS, rowptr, csr, dinv, b3, h3, N);

    // mean pool
    batch_count_kernel<<<1, 64, 0, stream>>>(batch, N, gcnt);
    pool_kernel<<<(N + 255) / 256, 128, 0, stream>>>(h3, batch, gsum, N);
    finalize_kernel<<<(NUM_GRAPHS * OUT_C + 255) / 256, 256, 0, stream>>>(gsum, gcnt, (float*)d_out);
}